// Round 7
// baseline (277.811 us; speedup 1.0000x reference)
//
#include <hip/hip_runtime.h>
#include <hip/hip_cooperative_groups.h>
#include <math.h>

#define N_ 64
#define L_ 256
#define D_ 1024
#define M_ 128
#define BK 64
#define NJOBS 768

typedef float f4 __attribute__((ext_vector_type(4)));
typedef short bf16x8 __attribute__((ext_vector_type(8)));
typedef short s8v __attribute__((ext_vector_type(8)));
typedef float f32x4 __attribute__((ext_vector_type(4)));

namespace cg = cooperative_groups;

// LDS tile layout: row stride 128B (64 bf16), 8 slots of 16B, slot XOR-swizzled by row
__device__ __forceinline__ int swz(int row, int slot) {
    return (row << 7) + (((slot) ^ (row & 7)) << 4);
}

// exactly 6 global_load_lds per thread (per wave) -- vmcnt counting depends on this
__device__ __forceinline__ void stage_tile(const short* __restrict__ A,
                                           const short* __restrict__ B,
                                           char* lds, int abase, int bbase,
                                           int k0, int tid) {
    int wofs = (tid >> 6) << 10;
    int r8 = tid >> 3;
    int sl = tid & 7;
#pragma unroll
    for (int i = 0; i < 4; ++i) {
        int row = i * 32 + r8;
        int ss = sl ^ (row & 7);
        __builtin_amdgcn_global_load_lds(
            (const __attribute__((address_space(1))) void*)(A + (size_t)row * D_ + k0 + (ss << 3)),
            (__attribute__((address_space(3))) void*)(lds + abase + (i << 12) + wofs),
            16, 0, 0);
    }
#pragma unroll
    for (int i = 0; i < 2; ++i) {
        int row = i * 32 + r8;
        int ss = sl ^ (row & 7);
        __builtin_amdgcn_global_load_lds(
            (const __attribute__((address_space(1))) void*)(B + (size_t)row * D_ + k0 + (ss << 3)),
            (__attribute__((address_space(3))) void*)(lds + bbase + (i << 12) + wofs),
            16, 0, 0);
    }
}

__device__ __forceinline__ void compute_tile(const char* lds, int abase, int bbase,
                                             int wr, int wc, int fr, int kg,
                                             f32x4 acc[4][2]) {
    bf16x8 a[4][2], b[2][2];
#pragma unroll
    for (int fi = 0; fi < 4; ++fi) {
        int row = (wr << 6) + (fi << 4) + fr;
#pragma unroll
        for (int kh = 0; kh < 2; ++kh)
            a[fi][kh] = *(const bf16x8*)(lds + abase + swz(row, (kh << 2) | kg));
    }
#pragma unroll
    for (int fj = 0; fj < 2; ++fj) {
        int col = (wc << 5) + (fj << 4) + fr;
#pragma unroll
        for (int kh = 0; kh < 2; ++kh)
            b[fj][kh] = *(const bf16x8*)(lds + bbase + swz(col, (kh << 2) | kg));
    }
    __builtin_amdgcn_s_setprio(1);
#pragma unroll
    for (int kh = 0; kh < 2; ++kh)
#pragma unroll
        for (int fi = 0; fi < 4; ++fi)
#pragma unroll
            for (int fj = 0; fj < 2; ++fj)
                acc[fi][fj] = __builtin_amdgcn_mfma_f32_16x16x32_bf16(a[fi][kh], b[fj][kh], acc[fi][fj], 0, 0, 0);
    __builtin_amdgcn_s_setprio(0);
}

// ============================ the whole op, one cooperative kernel ============================
__global__ __launch_bounds__(256, 3) void mega_kernel(
        const float* __restrict__ x, const float* __restrict__ y,
        const int* __restrict__ mask,
        short* __restrict__ xh, short* __restrict__ yh,
        float* __restrict__ sqx, float* __restrict__ sqy,
        float* __restrict__ ed_raw, float* __restrict__ edq,
        float* __restrict__ out) {
    __shared__ __align__(16) char lds[49152];
    int tid = threadIdx.x;
    int nb = gridDim.x;
    cg::grid_group gridg = cg::this_grid();

    // ---- phase 0: zero accumulators (block 0; d_ws/d_out arrive poisoned 0xAA) ----
    if (blockIdx.x == 0) {
        for (int i = tid; i < N_ * M_ + N_ + 1; i += 256) {
            if (i < N_ * M_)            ed_raw[i] = 0.f;
            else if (i < N_ * M_ + N_)  edq[i - N_ * M_] = 0.f;
            else                        out[0] = 0.f;
        }
    }

    // ---- phase 1: fp32 -> bf16 (RNE) + row sum-of-squares, x then y ----
    {
        int w = tid >> 6, lane = tid & 63;
        for (int row = blockIdx.x * 4 + w; row < N_ * L_ + M_; row += nb * 4) {
            const float* in; short* hi; float* ssq; int r;
            if (row < N_ * L_) { in = x; hi = xh; ssq = sqx; r = row; }
            else               { in = y; hi = yh; ssq = sqy; r = row - N_ * L_; }
            const f4* p = (const f4*)(in + (size_t)r * D_);
            float s = 0.f;
#pragma unroll
            for (int rep = 0; rep < 2; ++rep) {
                f4 v0 = p[rep * 128 + lane * 2];
                f4 v1 = p[rep * 128 + lane * 2 + 1];
                s8v h;
#pragma unroll
                for (int j = 0; j < 4; ++j) {
                    float f = v0[j]; s = fmaf(f, f, s);
                    unsigned u = __float_as_uint(f);
                    h[j] = (short)((u + 0x7FFFu + ((u >> 16) & 1u)) >> 16);
                }
#pragma unroll
                for (int j = 0; j < 4; ++j) {
                    float f = v1[j]; s = fmaf(f, f, s);
                    unsigned u = __float_as_uint(f);
                    h[4 + j] = (short)((u + 0x7FFFu + ((u >> 16) & 1u)) >> 16);
                }
                *(s8v*)(hi + (size_t)r * D_ + rep * 512 + lane * 8) = h;
            }
#pragma unroll
            for (int off = 32; off; off >>= 1) s += __shfl_down(s, off);
            if (lane == 0) ssq[r] = s;
        }
    }

    gridg.sync();

    // ---- phase 2: fused bf16 MFMA GEMM + sqrt/mask epilogue ----
    // XCD-grouped job mapping (job&7 -> XCD; XCD x owns n in [8x,8x+8)); per-XCD
    // bf16 working set ~4.25 MB =~ one L2 (verified FETCH 240 MB -> 17.6 MB).
    // K-loop: counted-vmcnt 2-phase; next-tile loads stay in flight across raw barriers.
    {
        int wid = tid >> 6, lane = tid & 63;
        int wr = wid >> 1, wc = wid & 1;
        int fr = lane & 15, kg = lane >> 4;

        for (int job = blockIdx.x; job < NJOBS; job += nb) {
            __syncthreads();   // protect LDS reuse across jobs (no-op when nb==NJOBS)

            int xcd = job & 7;
            int slot = job >> 3;            // 0..95
            int n = xcd * 8 + slot / 12;
            int r = slot % 12;

            int l0, c0, mode;
            const short *Ah, *Bh;
            if (r < 4) {
                mode = 0;
                l0 = (r >> 1) << 7; c0 = (r & 1) << 6;
                Bh = yh + (size_t)c0 * D_;
            } else {
                mode = 1;
                int rr = r - 4;
                l0 = (rr >> 2) << 7; c0 = (rr & 3) << 6;
                Bh = xh + ((size_t)n * L_ + c0) * D_;
            }
            Ah = xh + ((size_t)n * L_ + l0) * D_;

            f32x4 acc[4][2];
#pragma unroll
            for (int i = 0; i < 4; ++i)
#pragma unroll
                for (int j = 0; j < 2; ++j)
                    acc[i][j] = (f32x4){0.f, 0.f, 0.f, 0.f};

            int buf = 0;
            stage_tile(Ah, Bh, lds, 0, 16384, 0, tid);     // 6 loads in flight, no drain
            for (int t = 0; t < 15; ++t) {
                int nbuf = buf ^ 1;
                stage_tile(Ah, Bh, lds, nbuf * 24576, nbuf * 24576 + 16384, (t + 1) * BK, tid);
                // wait for the OLDER batch only; 6 next-tile loads stay in flight
                asm volatile("s_waitcnt vmcnt(6)" ::: "memory");
                __builtin_amdgcn_sched_barrier(0);
                __builtin_amdgcn_s_barrier();              // current-buffer stages landed
                compute_tile(lds, buf * 24576, buf * 24576 + 16384, wr, wc, fr, kg, acc);
                __builtin_amdgcn_sched_barrier(0);
                __builtin_amdgcn_s_barrier();              // reads done before restage
                buf = nbuf;
            }
            asm volatile("s_waitcnt vmcnt(0)" ::: "memory");
            __builtin_amdgcn_sched_barrier(0);
            __builtin_amdgcn_s_barrier();
            compute_tile(lds, buf * 24576, buf * 24576 + 16384, wr, wc, fr, kg, acc);

            int rbase = (lane >> 4) << 2;

            if (mode == 0) {
                float sy[2];
#pragma unroll
                for (int fj = 0; fj < 2; ++fj)
                    sy[fj] = sqy[c0 + (wc << 5) + (fj << 4) + fr];
                float colsum[2] = {0.f, 0.f};
#pragma unroll
                for (int fi = 0; fi < 4; ++fi) {
#pragma unroll
                    for (int rr = 0; rr < 4; ++rr) {
                        int gl = l0 + (wr << 6) + (fi << 4) + rbase + rr;
                        float sx = sqx[n * L_ + gl];
                        float mf = (float)mask[n * L_ + gl];
#pragma unroll
                        for (int fj = 0; fj < 2; ++fj) {
                            float raw = fmaf(-2.f, acc[fi][fj][rr], sx + sy[fj]);
                            float dd = raw > 0.f ? sqrtf(raw) : 0.f;
                            colsum[fj] = fmaf(dd, mf, colsum[fj]);
                        }
                    }
                }
#pragma unroll
                for (int fj = 0; fj < 2; ++fj) {
                    colsum[fj] += __shfl_xor(colsum[fj], 16);
                    colsum[fj] += __shfl_xor(colsum[fj], 32);
                }
                if (lane < 16) {
#pragma unroll
                    for (int fj = 0; fj < 2; ++fj)
                        atomicAdd(&ed_raw[n * M_ + c0 + (wc << 5) + (fj << 4) + lane], colsum[fj]);
                }
            } else {
                int gj[2];
                float sj[2], mj[2];
#pragma unroll
                for (int fj = 0; fj < 2; ++fj) {
                    gj[fj] = c0 + (wc << 5) + (fj << 4) + fr;
                    sj[fj] = sqx[n * L_ + gj[fj]];
                    mj[fj] = (float)mask[n * L_ + gj[fj]];
                }
                float tot = 0.f;
#pragma unroll
                for (int fi = 0; fi < 4; ++fi) {
#pragma unroll
                    for (int rr = 0; rr < 4; ++rr) {
                        int gl = l0 + (wr << 6) + (fi << 4) + rbase + rr;
                        float sx = sqx[n * L_ + gl];
                        float mf = (float)mask[n * L_ + gl];
#pragma unroll
                        for (int fj = 0; fj < 2; ++fj) {
                            float raw = fmaf(-2.f, acc[fi][fj][rr], sx + sj[fj]);
                            float dd = raw > 0.f ? sqrtf(raw) : 0.f;
                            if (gl == gj[fj]) dd = 0.f;   // exact-zero diagonal
                            tot = fmaf(dd * mf, mj[fj], tot);
                        }
                    }
                }
#pragma unroll
                for (int off = 32; off; off >>= 1) tot += __shfl_xor(tot, off);
                if (lane == 0) atomicAdd(&edq[n], tot);
            }
        }
    }

    gridg.sync();

    // ---- phase 3: per-n log-softmax -> loss (64 parallel jobs) ----
    {
        float* f = (float*)lds;
        for (int n = blockIdx.x; n < N_; n += nb) {
            __syncthreads();
            float sc = 0.f, Sn, mx, se;
            if (tid < 128) {
                int s = mask[n * L_ + tid] + mask[n * L_ + 128 + tid];
#pragma unroll
                for (int off = 32; off; off >>= 1) s += __shfl_down(s, off);
                if ((tid & 63) == 0) f[4 + (tid >> 6)] = (float)s;
            }
            __syncthreads();
            Sn = f[4] + f[5];
            float valid1 = fmaxf(Sn, 1.f);
            float edq_n = edq[n] / fmaxf(Sn * Sn, 1.f);
            if (tid < 128) {
                sc = -20.f * (2.f * ed_raw[n * M_ + tid] / valid1 - edq_n);
                mx = sc;
#pragma unroll
                for (int off = 32; off; off >>= 1) mx = fmaxf(mx, __shfl_xor(mx, off));
                if ((tid & 63) == 0) f[6 + (tid >> 6)] = mx;
                if (tid == n) f[8] = sc;
            }
            __syncthreads();
            mx = fmaxf(f[6], f[7]);
            if (tid < 128) {
                se = expf(sc - mx);
#pragma unroll
                for (int off = 32; off; off >>= 1) se += __shfl_xor(se, off);
                if ((tid & 63) == 0) f[10 + (tid >> 6)] = se;
            }
            __syncthreads();
            if (tid == 0) {
                float sesum = f[10] + f[11];
                float lossn = -(f[8] - mx - logf(sesum));
                atomicAdd(out, lossn * (1.f / (float)N_));
            }
        }
    }
}

extern "C" void kernel_launch(void* const* d_in, const int* in_sizes, int n_in,
                              void* d_out, int out_size, void* d_ws, size_t ws_size,
                              hipStream_t stream) {
    const float* x = (const float*)d_in[0];
    const float* y = (const float*)d_in[1];
    const int* mask = (const int*)d_in[2];

    char* base = (char*)d_ws;
    float* sqx    = (float*)(base);           // 16384 f
    float* sqy    = (float*)(base + 65536);   // 128 f
    float* ed_raw = (float*)(base + 66048);   // 8192 f
    float* edq    = (float*)(base + 98816);   // 64 f
    short* xh = (short*)(base + (1 << 20));   // 16.78M shorts
    short* yh = xh + 16777216;                // 131072 shorts
    float* out = (float*)d_out;

    int maxb = 0;
    hipOccupancyMaxActiveBlocksPerMultiprocessor(&maxb, mega_kernel, 256, 0);
    if (maxb < 1) maxb = 1;
    int grid = maxb * 256;                    // 256 CUs on MI355X
    if (grid > NJOBS) grid = NJOBS;

    void* args[] = {(void*)&x, (void*)&y, (void*)&mask, (void*)&xh, (void*)&yh,
                    (void*)&sqx, (void*)&sqy, (void*)&ed_raw, (void*)&edq, (void*)&out};
    hipLaunchCooperativeKernel(mega_kernel, dim3(grid), dim3(256), args, 0, stream);
}

// Round 8
// 143.742 us; speedup vs baseline: 1.9327x; 1.9327x over previous
//
#include <hip/hip_runtime.h>
#include <math.h>

#define N_ 64
#define L_ 256
#define D_ 1024
#define M_ 128
#define BKW 32

typedef float f4 __attribute__((ext_vector_type(4)));
typedef short bf16x8 __attribute__((ext_vector_type(8)));
typedef short s8v __attribute__((ext_vector_type(8)));
typedef float f32x4 __attribute__((ext_vector_type(4)));
typedef int i4 __attribute__((ext_vector_type(4)));

// ---------------- fp32 -> bf16 (RNE) + row sum-of-squares (x and y fused) ----------------
__global__ __launch_bounds__(256) void convert_ssq_kernel(const float* __restrict__ x,
                                                          const float* __restrict__ y,
                                                          short* __restrict__ xh,
                                                          short* __restrict__ yh,
                                                          float* __restrict__ sqx,
                                                          float* __restrict__ sqy) {
    int w = threadIdx.x >> 6, lane = threadIdx.x & 63;
    int row = blockIdx.x * 4 + w;
    const float* in;
    short* hi;
    float* ssq;
    int r;
    if (row < N_ * L_) { in = x; hi = xh; ssq = sqx; r = row; }
    else               { in = y; hi = yh; ssq = sqy; r = row - N_ * L_; }
    const f4* p = (const f4*)(in + (size_t)r * D_);
    float s = 0.f;
#pragma unroll
    for (int rep = 0; rep < 2; ++rep) {
        f4 v0 = p[rep * 128 + lane * 2];
        f4 v1 = p[rep * 128 + lane * 2 + 1];
        s8v h;
#pragma unroll
        for (int j = 0; j < 4; ++j) {
            float f = v0[j]; s = fmaf(f, f, s);
            unsigned u = __float_as_uint(f);
            h[j] = (short)((u + 0x7FFFu + ((u >> 16) & 1u)) >> 16);
        }
#pragma unroll
        for (int j = 0; j < 4; ++j) {
            float f = v1[j]; s = fmaf(f, f, s);
            unsigned u = __float_as_uint(f);
            h[4 + j] = (short)((u + 0x7FFFu + ((u >> 16) & 1u)) >> 16);
        }
        *(s8v*)(hi + (size_t)r * D_ + rep * 512 + lane * 8) = h;
    }
#pragma unroll
    for (int off = 32; off; off >>= 1) s += __shfl_down(s, off);
    if (lane == 0) ssq[r] = s;
}

// Wave-private LDS tile: 64 rows x 32 k bf16 = 64 rows x 64B; 4 slots of 16B per row,
// slot XOR-swizzled by row so ds_read_b128 per 16-lane group is <=2-way (free).
__device__ __forceinline__ int wswz(int row, int kg) {
    return (row << 6) + (((kg ^ (row & 3) ^ ((row >> 2) & 3)) & 3) << 4);
}

// exactly 8 global_load_lds per wave -- vmcnt counting depends on this
__device__ __forceinline__ void wstage(const short* __restrict__ A,
                                       const short* __restrict__ B,
                                       char* wlds, int bufofs, int k0, int lane) {
    int row4 = lane >> 2;   // 0..15
    int sl = lane & 3;
#pragma unroll
    for (int i = 0; i < 4; ++i) {
        int row = (i << 4) + row4;
        int ss = sl ^ (row & 3) ^ ((row >> 2) & 3);
        __builtin_amdgcn_global_load_lds(
            (const __attribute__((address_space(1))) void*)(A + (size_t)row * D_ + k0 + (ss << 3)),
            (__attribute__((address_space(3))) void*)(wlds + bufofs + (i << 10)),
            16, 0, 0);
    }
#pragma unroll
    for (int i = 0; i < 4; ++i) {
        int row = (i << 4) + row4;
        int ss = sl ^ (row & 3) ^ ((row >> 2) & 3);
        __builtin_amdgcn_global_load_lds(
            (const __attribute__((address_space(1))) void*)(B + (size_t)row * D_ + k0 + (ss << 3)),
            (__attribute__((address_space(3))) void*)(wlds + bufofs + 4096 + (i << 10)),
            16, 0, 0);
    }
}

__device__ __forceinline__ void wcompute(const char* wlds, int bufofs,
                                         int fr, int kg, f32x4 acc[4][4]) {
    bf16x8 a[4], b[4];
#pragma unroll
    for (int fi = 0; fi < 4; ++fi)
        a[fi] = *(const bf16x8*)(wlds + bufofs + wswz((fi << 4) + fr, kg));
#pragma unroll
    for (int fj = 0; fj < 4; ++fj)
        b[fj] = *(const bf16x8*)(wlds + bufofs + 4096 + wswz((fj << 4) + fr, kg));
    __builtin_amdgcn_s_setprio(1);
#pragma unroll
    for (int fi = 0; fi < 4; ++fi)
#pragma unroll
        for (int fj = 0; fj < 4; ++fj)
            acc[fi][fj] = __builtin_amdgcn_mfma_f32_16x16x32_bf16(a[fi], b[fj], acc[fi][fj], 0, 0, 0);
    __builtin_amdgcn_s_setprio(0);
}

// ---------------- fused bf16 MFMA GEMM + sqrt/mask epilogue, BARRIER-FREE ----------------
// 2 waves/block, each wave owns one 64x64 output tile + private 16KB LDS double-buffer.
// Sync is per-wave s_waitcnt vmcnt only -- no __syncthreads in the K-loop.
// XCD-grouped job map (block b -> XCD b&7; XCD x owns n in [8x,8x+8)): per-XCD bf16
// working set ~4.25 MB =~ one L2 (verified FETCH 240 MB -> 17.6 MB in R5).
__global__ __launch_bounds__(128) void ed_mfma_kernel(
        const short* __restrict__ xh, const short* __restrict__ yh,
        const float* __restrict__ sqx, const float* __restrict__ sqy,
        const int* __restrict__ mask,
        float* __restrict__ ed_raw, float* __restrict__ edq) {
    __shared__ __align__(16) char lds[32768];   // 2 waves x [A0 4K][B0 4K][A1 4K][B1 4K]
    int tid = threadIdx.x;
    int wid = tid >> 6, lane = tid & 63;
    char* wlds = lds + (wid << 14);

    int b = blockIdx.x;
    int xcd = b & 7;
    int slot = b >> 3;                 // 0..95
    int n = xcd * 8 + slot / 12;
    int w = (slot % 12) * 2 + wid;     // 0..23 wave-jobs per n

    int l0, c0, mode;
    const short *A, *B;
    if (w < 8) {                       // edxy: 4 x 2 tiles of 64x64 (L x M)
        mode = 0;
        l0 = (w >> 1) << 6; c0 = (w & 1) << 6;
        B = yh + (size_t)c0 * D_;
    } else {                           // edxx: 4 x 4 tiles of 64x64 (L x L)
        mode = 1;
        int u = w - 8;
        l0 = (u >> 2) << 6; c0 = (u & 3) << 6;
        B = xh + ((size_t)n * L_ + c0) * D_;
    }
    A = xh + ((size_t)n * L_ + l0) * D_;

    f32x4 acc[4][4];
#pragma unroll
    for (int i = 0; i < 4; ++i)
#pragma unroll
        for (int j = 0; j < 4; ++j)
            acc[i][j] = (f32x4){0.f, 0.f, 0.f, 0.f};

    int fr = lane & 15, kg = lane >> 4;

    int buf = 0;
    wstage(A, B, wlds, 0, 0, lane);    // 8 loads in flight
    for (int t = 0; t < 31; ++t) {
        wstage(A, B, wlds, (buf ^ 1) << 13, (t + 1) * BKW, lane);   // 8 more
        asm volatile("s_waitcnt vmcnt(8)" ::: "memory");            // older batch landed
        __builtin_amdgcn_sched_barrier(0);
        wcompute(wlds, buf << 13, fr, kg, acc);
        buf ^= 1;
    }
    asm volatile("s_waitcnt vmcnt(0)" ::: "memory");
    __builtin_amdgcn_sched_barrier(0);
    wcompute(wlds, buf << 13, fr, kg, acc);

    // ---- epilogue: d = sqrt(max(sqx+sqy-2g,0)) * mask, reduce over rows ----
    if (mode == 0) {
        float sy[4];
#pragma unroll
        for (int fj = 0; fj < 4; ++fj)
            sy[fj] = sqy[c0 + (fj << 4) + fr];
        float colsum[4] = {0.f, 0.f, 0.f, 0.f};
#pragma unroll
        for (int fi = 0; fi < 4; ++fi) {
#pragma unroll
            for (int r = 0; r < 4; ++r) {
                int gl = l0 + (fi << 4) + (kg << 2) + r;
                float sx = sqx[n * L_ + gl];
                float mf = (float)mask[n * L_ + gl];
#pragma unroll
                for (int fj = 0; fj < 4; ++fj) {
                    float raw = fmaf(-2.f, acc[fi][fj][r], sx + sy[fj]);
                    float dd = raw > 0.f ? sqrtf(raw) : 0.f;
                    colsum[fj] = fmaf(dd, mf, colsum[fj]);
                }
            }
        }
#pragma unroll
        for (int fj = 0; fj < 4; ++fj) {
            colsum[fj] += __shfl_xor(colsum[fj], 16);
            colsum[fj] += __shfl_xor(colsum[fj], 32);
        }
        if (lane < 16) {
#pragma unroll
            for (int fj = 0; fj < 4; ++fj)
                atomicAdd(&ed_raw[n * M_ + c0 + (fj << 4) + lane], colsum[fj]);
        }
    } else {
        int gj[4];
        float sj[4], mj[4];
#pragma unroll
        for (int fj = 0; fj < 4; ++fj) {
            gj[fj] = c0 + (fj << 4) + fr;
            sj[fj] = sqx[n * L_ + gj[fj]];
            mj[fj] = (float)mask[n * L_ + gj[fj]];
        }
        float tot = 0.f;
#pragma unroll
        for (int fi = 0; fi < 4; ++fi) {
#pragma unroll
            for (int r = 0; r < 4; ++r) {
                int gl = l0 + (fi << 4) + (kg << 2) + r;
                float sx = sqx[n * L_ + gl];
                float mf = (float)mask[n * L_ + gl];
#pragma unroll
                for (int fj = 0; fj < 4; ++fj) {
                    float raw = fmaf(-2.f, acc[fi][fj][r], sx + sj[fj]);
                    float dd = raw > 0.f ? sqrtf(raw) : 0.f;
                    if (gl == gj[fj]) dd = 0.f;   // exact-zero diagonal
                    tot = fmaf(dd * mf, mj[fj], tot);
                }
            }
        }
#pragma unroll
        for (int off = 32; off; off >>= 1) tot += __shfl_xor(tot, off);
        if (lane == 0) atomicAdd(&edq[n], tot);
    }
}

// ---------------- final: mask sums + scores -> log_softmax -> loss ----------------
__global__ __launch_bounds__(256) void score_kernel(const float* __restrict__ ed_raw,
                                                    const float* __restrict__ edq,
                                                    const int* __restrict__ mask,
                                                    float* __restrict__ out) {
    __shared__ float sc[N_ * M_];   // 32 KB
    __shared__ float Ssh[N_];
    __shared__ float red[N_];
    int tid = threadIdx.x;
    {   // mask sums: thread t sums 64 consecutive ints; 4 threads per n
        const i4* mp = (const i4*)(mask + tid * 64);
        int s = 0;
#pragma unroll
        for (int i = 0; i < 16; ++i) { i4 v = mp[i]; s += v[0] + v[1] + v[2] + v[3]; }
        s += __shfl_xor(s, 1);
        s += __shfl_xor(s, 2);
        if ((tid & 3) == 0) Ssh[tid >> 2] = (float)s;
    }
    __syncthreads();
    for (int i = tid; i < N_ * M_; i += 256) {
        int n = i >> 7;
        float Sn = Ssh[n];
        float valid1 = fmaxf(Sn, 1.f);
        float edq_n = edq[n] / fmaxf(Sn * Sn, 1.f);
        sc[i] = -20.f * (2.f * ed_raw[i] / valid1 - edq_n);
    }
    __syncthreads();
    int n = tid >> 2, q = tid & 3;
    const float* row = sc + n * M_;
    float mx = -INFINITY;
    for (int m = q * 32; m < q * 32 + 32; ++m) mx = fmaxf(mx, row[m]);
    mx = fmaxf(mx, __shfl_xor(mx, 1));
    mx = fmaxf(mx, __shfl_xor(mx, 2));
    float se = 0.f;
    for (int m = q * 32; m < q * 32 + 32; ++m) se += expf(row[m] - mx);
    se += __shfl_xor(se, 1);
    se += __shfl_xor(se, 2);
    if (q == 0) red[n] = -(row[n] - mx - logf(se));
    __syncthreads();
    if (tid < 64) {
        float v = red[tid];
#pragma unroll
        for (int off = 32; off; off >>= 1) v += __shfl_down(v, off);
        if (tid == 0) out[0] = v * (1.f / (float)N_);
    }
}

extern "C" void kernel_launch(void* const* d_in, const int* in_sizes, int n_in,
                              void* d_out, int out_size, void* d_ws, size_t ws_size,
                              hipStream_t stream) {
    const float* x = (const float*)d_in[0];
    const float* y = (const float*)d_in[1];
    const int* mask = (const int*)d_in[2];

    char* base = (char*)d_ws;
    float* sqx    = (float*)(base);           // 16384 f
    float* sqy    = (float*)(base + 65536);   // 128 f
    float* ed_raw = (float*)(base + 66048);   // 8192 f
    float* edq    = (float*)(base + 98816);   // 64 f
    short* xh = (short*)(base + (1 << 20));   // 16.78M shorts
    short* yh = xh + 16777216;                // 131072 shorts

    hipMemsetAsync(base + 66048, 0, 33024, stream);  // ed_raw + edq

    convert_ssq_kernel<<<(N_ * L_ + M_) / 4, 256, 0, stream>>>(x, y, xh, yh, sqx, sqy);

    ed_mfma_kernel<<<768, 128, 0, stream>>>(xh, yh, sqx, sqy, mask, ed_raw, edq);

    score_kernel<<<1, 256, 0, stream>>>(ed_raw, edq, mask, (float*)d_out);
}